// Round 1
// baseline (248.175 us; speedup 1.0000x reference)
//
#include <hip/hip_runtime.h>

// ---------------------------------------------------------------------------
// DynamicEncoder: 2-stage masked skeleton conv (K=15, stride 2, pad 7) with
// channel-pooling folded into precomputed fused weights.
//
// Stage 1: x (64,2047,100)[+zero frame @2047] -> y0 (64,112,1024)
// Stage 2: y0 -> out (64,112,512)
//
// Workspace layout (floats):
//   W0c  [14 pools][7 slots][4 ci][8 c][16 k]   = 50176
//   W1c  [ 7 pools][8 slots][8 ci][16 c][16 k]  = 114688
//   bf0  [112], bf1 [112]
//   y0   [64][112][1024]                        = 7340032
// ---------------------------------------------------------------------------

#define N_W0C   50176
#define N_W1C   114688
#define OFF_W0C 0
#define OFF_W1C 50176
#define OFF_BF0 164864
#define OFF_BF1 164976
#define OFF_Y0  165120
#define N_Y0    7340032

// ---- graph constants (hand-derived from reference, verified) ----
__constant__ int c_pool0_len[14] = {2,2,2,2,1,2,2,1,2,2,1,2,2,2};
__constant__ int c_pool0_mem[14][2] = {{0,3},{6,9},{1,4},{7,10},{2,2},{5,8},{11,14},{12,12},
                                       {15,17},{19,21},{13,13},{16,18},{20,22},{23,24}};
__constant__ int c_un0_len[14] = {7,3,7,3,6,6,5,5,4,3,5,4,3,6};
__constant__ int c_un0[14][7] = {
 {0,1,2,3,6,23,24},
 {3,6,9,0,0,0,0},
 {0,1,2,4,7,23,24},
 {4,7,10,0,0,0,0},
 {0,1,2,5,23,24,0},
 {2,5,8,11,12,13,0},
 {8,11,12,13,14,0,0},
 {8,11,12,13,15,0,0},
 {12,15,17,19,0,0,0},
 {17,19,21,0,0,0,0},
 {8,11,12,13,16,0,0},
 {13,16,18,20,0,0,0},
 {18,20,22,0,0,0,0},
 {0,1,2,3,23,24,0}
};
__constant__ unsigned c_nbm0[25] = {
 0x180000Fu,0x1800017u,0x1800027u,0x1800049u,0x92u,0x124u,0x248u,0x490u,
 0x3920u,0x240u,0x480u,0x7900u,0xB900u,0x13900u,0x4800u,0x29000u,
 0x52000u,0xA8000u,0x150000u,0x2A0000u,0x540000u,0x280000u,0x500000u,
 0x180000Fu,0x180000Fu
};
// wave-pool pairing permutation: pairs pools of equal union length per wave
__constant__ int c_order0[14] = {0,2,1,3,4,5,6,7,8,11,9,12,10,13};

__constant__ int c_pool1_len[7] = {2,2,2,1,3,3,1};
__constant__ int c_pool1_mem[7][3] = {{0,1,1},{2,3,3},{4,5,5},{6,6,6},{7,8,9},{10,11,12},{13,13,13}};
__constant__ int c_un1_len[7] = {5,5,8,4,6,6,5};
__constant__ int c_un1[7][8] = {
 {0,1,2,4,13,0,0,0},
 {0,2,3,4,13,0,0,0},
 {0,2,4,5,6,7,10,13},
 {5,6,7,10,0,0,0,0},
 {5,6,7,8,9,10,0,0},
 {5,6,7,10,11,12,0,0},
 {0,1,2,4,13,0,0,0}
};
__constant__ unsigned c_nbm1[14] = {
 0x2017u,0x2003u,0x201Du,0xCu,0x2035u,0x4F0u,0x4E0u,0x5E0u,
 0x380u,0x300u,0xCE0u,0x1C00u,0x1800u,0x2017u
};

// ---------------------------------------------------------------------------
// Prep: fold P (pool mean) and MASK into compact per-pool weights + biases.
// ---------------------------------------------------------------------------
__global__ void prep_fused_weights(const float* __restrict__ w0, const float* __restrict__ b0,
                                   const float* __restrict__ w1, const float* __restrict__ b1,
                                   float* __restrict__ ws) {
  int t = blockIdx.x * blockDim.x + threadIdx.x;
  if (t < N_W0C) {
    // layout: (((i*7+s)*4+ci)*8+c)*16 + k
    int k  = t & 15;
    int c  = (t >> 4) & 7;
    int ci = (t >> 7) & 3;
    int r  = t >> 9;       // i*7+s
    int i  = r / 7;
    int s  = r - i * 7;
    float v = 0.f;
    if (k < 15 && s < c_un0_len[i]) {
      int m = c_un0[i][s];
      int L = c_pool0_len[i];
      for (int jj = 0; jj < L; ++jj) {
        int j = c_pool0_mem[i][jj];
        if ((c_nbm0[j] >> m) & 1u)
          v += w0[(j * 8 + c) * 1500 + (m * 4 + ci) * 15 + k];
      }
      v *= 1.f / (float)L;
    }
    ws[OFF_W0C + t] = v;
  } else if (t < N_W0C + N_W1C) {
    int t2 = t - N_W0C;
    // layout: (((i*8+s)*8+ci)*16+c)*16 + k
    int k  = t2 & 15;
    int c  = (t2 >> 4) & 15;
    int ci = (t2 >> 8) & 7;
    int s  = (t2 >> 11) & 7;
    int i  = t2 >> 14;
    float v = 0.f;
    if (k < 15 && s < c_un1_len[i]) {
      int m = c_un1[i][s];
      int L = c_pool1_len[i];
      for (int jj = 0; jj < L; ++jj) {
        int j = c_pool1_mem[i][jj];
        if ((c_nbm1[j] >> m) & 1u)
          v += w1[(j * 16 + c) * 1680 + (m * 8 + ci) * 15 + k];
      }
      v *= 1.f / (float)L;
    }
    ws[OFF_W1C + t2] = v;
  } else if (t < N_W0C + N_W1C + 112) {
    int p = t - (N_W0C + N_W1C);
    int i = p >> 3, c = p & 7;
    int L = c_pool0_len[i];
    float v = 0.f;
    for (int jj = 0; jj < L; ++jj) v += b0[c_pool0_mem[i][jj] * 8 + c];
    ws[OFF_BF0 + p] = v / (float)L;
  } else if (t < N_W0C + N_W1C + 224) {
    int p = t - (N_W0C + N_W1C + 112);
    int i = p >> 4, c = p & 15;
    int L = c_pool1_len[i];
    float v = 0.f;
    for (int jj = 0; jj < L; ++jj) v += b1[c_pool1_mem[i][jj] * 16 + c];
    ws[OFF_BF1 + p] = v / (float)L;
  }
}

// ---------------------------------------------------------------------------
// Stage 1: fused sparse conv + bias + pool + relu.
// Block: (t-tile of 64, batch b). 448 threads = 112 pooled channels x 4 strips
// of 16 t each. x tile staged in LDS as [cin][time] (142 frames, stride 144).
// ---------------------------------------------------------------------------
__global__ __launch_bounds__(448) void conv_stage1(const float* __restrict__ x,
                                                   const float* __restrict__ ws,
                                                   float* __restrict__ y0) {
  __shared__ float xs[100 * 144];  // 57.6 KB
  const int tid = threadIdx.x;
  const int b = blockIdx.y;
  const int t0 = blockIdx.x << 6;
  const int g0 = 2 * t0 - 7;
  const float* __restrict__ xb = x + (size_t)b * (2047 * 100);
  for (int e = tid; e < 14200; e += 448) {
    int lt = e / 100;
    int cin = e - lt * 100;
    int gt = g0 + lt;
    float v = (gt >= 0 && gt < 2047) ? xb[gt * 100 + cin] : 0.f;
    xs[cin * 144 + lt] = v;
  }
  __syncthreads();

  const int vp = tid >> 2;
  const int tt0 = (tid & 3) << 4;       // 16-t strip
  const int i = c_order0[vp >> 3];      // pool index (wave-paired by length)
  const int c = vp & 7;
  float acc[16];
#pragma unroll
  for (int q = 0; q < 16; ++q) acc[q] = 0.f;

  const int len = c_un0_len[i];
  const float* __restrict__ W0c = ws + OFF_W0C;
  for (int s = 0; s < len; ++s) {
    const int m = c_un0[i][s];
#pragma unroll
    for (int ci = 0; ci < 4; ++ci) {
      const float* xp = xs + (m * 4 + ci) * 144 + 2 * tt0;
      float xr[48];
#pragma unroll
      for (int q = 0; q < 12; ++q) {
        float4 v4 = *reinterpret_cast<const float4*>(xp + 4 * q);
        xr[4*q+0] = v4.x; xr[4*q+1] = v4.y; xr[4*q+2] = v4.z; xr[4*q+3] = v4.w;
      }
      const float* wp = W0c + ((((i * 7 + s) * 4 + ci) * 8 + c) << 4);
      float wk[16];
#pragma unroll
      for (int q = 0; q < 4; ++q) {
        float4 v4 = *reinterpret_cast<const float4*>(wp + 4 * q);
        wk[4*q+0] = v4.x; wk[4*q+1] = v4.y; wk[4*q+2] = v4.z; wk[4*q+3] = v4.w;
      }
#pragma unroll
      for (int k = 0; k < 15; ++k)
#pragma unroll
        for (int tt = 0; tt < 16; ++tt)
          acc[tt] = fmaf(wk[k], xr[2 * tt + k], acc[tt]);
    }
  }
  const int p = (i << 3) + c;
  const float bb = ws[OFF_BF0 + p];
  float* __restrict__ yp = y0 + (((size_t)b * 112 + p) << 10) + t0 + tt0;
#pragma unroll
  for (int q = 0; q < 4; ++q) {
    float4 o;
    o.x = fmaxf(acc[4*q+0] + bb, 0.f);
    o.y = fmaxf(acc[4*q+1] + bb, 0.f);
    o.z = fmaxf(acc[4*q+2] + bb, 0.f);
    o.w = fmaxf(acc[4*q+3] + bb, 0.f);
    *reinterpret_cast<float4*>(yp + 4 * q) = o;
  }
}

// ---------------------------------------------------------------------------
// Stage 2: same structure; input y0 is [b][112][1024]; each wave = one pool.
// ---------------------------------------------------------------------------
__global__ __launch_bounds__(448) void conv_stage2(const float* __restrict__ ws,
                                                   float* __restrict__ out) {
  __shared__ float xs[112 * 144];  // 64.5 KB
  const int tid = threadIdx.x;
  const int b = blockIdx.y;
  const int t0 = blockIdx.x << 6;
  const int g0 = 2 * t0 - 7;
  const float* __restrict__ y0 = ws + OFF_Y0 + (size_t)b * (112 * 1024);
  for (int e = tid; e < 15904; e += 448) {
    int lt = e / 112;
    int cin = e - lt * 112;
    int gt = g0 + lt;
    float v = (gt >= 0 && gt < 1024) ? y0[(cin << 10) + gt] : 0.f;
    xs[cin * 144 + lt] = v;
  }
  __syncthreads();

  const int vp = tid >> 2;
  const int tt0 = (tid & 3) << 4;
  const int i = vp >> 4;    // pool 0..6, one per wave
  const int c = vp & 15;
  float acc[16];
#pragma unroll
  for (int q = 0; q < 16; ++q) acc[q] = 0.f;

  const int len = c_un1_len[i];
  const float* __restrict__ W1c = ws + OFF_W1C;
  for (int s = 0; s < len; ++s) {
    const int m = c_un1[i][s];
#pragma unroll
    for (int ci = 0; ci < 8; ++ci) {
      const float* xp = xs + (m * 8 + ci) * 144 + 2 * tt0;
      float xr[48];
#pragma unroll
      for (int q = 0; q < 12; ++q) {
        float4 v4 = *reinterpret_cast<const float4*>(xp + 4 * q);
        xr[4*q+0] = v4.x; xr[4*q+1] = v4.y; xr[4*q+2] = v4.z; xr[4*q+3] = v4.w;
      }
      const float* wp = W1c + ((((i * 8 + s) * 8 + ci) * 16 + c) << 4);
      float wk[16];
#pragma unroll
      for (int q = 0; q < 4; ++q) {
        float4 v4 = *reinterpret_cast<const float4*>(wp + 4 * q);
        wk[4*q+0] = v4.x; wk[4*q+1] = v4.y; wk[4*q+2] = v4.z; wk[4*q+3] = v4.w;
      }
#pragma unroll
      for (int k = 0; k < 15; ++k)
#pragma unroll
        for (int tt = 0; tt < 16; ++tt)
          acc[tt] = fmaf(wk[k], xr[2 * tt + k], acc[tt]);
    }
  }
  const int p = (i << 4) + c;
  const float bb = ws[OFF_BF1 + p];
  float* __restrict__ op = out + (((size_t)b * 112 + p) << 9) + t0 + tt0;
#pragma unroll
  for (int q = 0; q < 4; ++q) {
    float4 o;
    o.x = fmaxf(acc[4*q+0] + bb, 0.f);
    o.y = fmaxf(acc[4*q+1] + bb, 0.f);
    o.z = fmaxf(acc[4*q+2] + bb, 0.f);
    o.w = fmaxf(acc[4*q+3] + bb, 0.f);
    *reinterpret_cast<float4*>(op + 4 * q) = o;
  }
}

extern "C" void kernel_launch(void* const* d_in, const int* in_sizes, int n_in,
                              void* d_out, int out_size, void* d_ws, size_t ws_size,
                              hipStream_t stream) {
  const float* x  = (const float*)d_in[0];
  const float* w0 = (const float*)d_in[1];
  const float* b0 = (const float*)d_in[2];
  const float* w1 = (const float*)d_in[3];
  const float* b1 = (const float*)d_in[4];
  float* ws  = (float*)d_ws;
  float* out = (float*)d_out;

  const int prep_total = N_W0C + N_W1C + 224;
  prep_fused_weights<<<(prep_total + 255) / 256, 256, 0, stream>>>(w0, b0, w1, b1, ws);
  conv_stage1<<<dim3(16, 64), 448, 0, stream>>>(x, ws, ws + OFF_Y0);
  conv_stage2<<<dim3(8, 64), 448, 0, stream>>>(ws, out);
}

// Round 2
// 208.014 us; speedup vs baseline: 1.1931x; 1.1931x over previous
//
#include <hip/hip_runtime.h>

// ---------------------------------------------------------------------------
// DynamicEncoder: 2-stage masked skeleton conv (K=15, stride 2, pad 7) with
// channel-pooling folded into precomputed fused weights.
//
// Round 2: bf16 LDS staging (halves LDS bytes + LDS read instrs), XOR bank
// swizzle on all LDS b128 accesses, bf16 y0 intermediate. Math stays fp32.
//
// Workspace layout:
//   floats: W0c [14][7][4][8][16] = 50176 | W1c [7][8][8][16][16] = 114688
//           bf0 [112] | bf1 [112]                       (ends at float 165120)
//   bytes:  OFF_Y0B = 660480: y0 bf16 [64][112][1024]   (14.68 MB)
// ---------------------------------------------------------------------------

#define N_W0C   50176
#define N_W1C   114688
#define OFF_W0C 0
#define OFF_W1C 50176
#define OFF_BF0 164864
#define OFF_BF1 164976
#define OFF_Y0B 660480u

#define S_STRIDE_B 304   // LDS row stride in bytes (152 bf16 >= 142 frames)

typedef unsigned int  uint32;
typedef unsigned short ushort16;

// ---- graph constants (hand-derived from reference, verified in round 1) ----
__constant__ int c_pool0_len[14] = {2,2,2,2,1,2,2,1,2,2,1,2,2,2};
__constant__ int c_pool0_mem[14][2] = {{0,3},{6,9},{1,4},{7,10},{2,2},{5,8},{11,14},{12,12},
                                       {15,17},{19,21},{13,13},{16,18},{20,22},{23,24}};
__constant__ int c_un0_len[14] = {7,3,7,3,6,6,5,5,4,3,5,4,3,6};
__constant__ int c_un0[14][7] = {
 {0,1,2,3,6,23,24},
 {3,6,9,0,0,0,0},
 {0,1,2,4,7,23,24},
 {4,7,10,0,0,0,0},
 {0,1,2,5,23,24,0},
 {2,5,8,11,12,13,0},
 {8,11,12,13,14,0,0},
 {8,11,12,13,15,0,0},
 {12,15,17,19,0,0,0},
 {17,19,21,0,0,0,0},
 {8,11,12,13,16,0,0},
 {13,16,18,20,0,0,0},
 {18,20,22,0,0,0,0},
 {0,1,2,3,23,24,0}
};
__constant__ unsigned c_nbm0[25] = {
 0x180000Fu,0x1800017u,0x1800027u,0x1800049u,0x92u,0x124u,0x248u,0x490u,
 0x3920u,0x240u,0x480u,0x7900u,0xB900u,0x13900u,0x4800u,0x29000u,
 0x52000u,0xA8000u,0x150000u,0x2A0000u,0x540000u,0x280000u,0x500000u,
 0x180000Fu,0x180000Fu
};
// wave-pool pairing permutation: pairs pools of equal union length per wave
__constant__ int c_order0[14] = {0,2,1,3,4,5,6,7,8,11,9,12,10,13};

__constant__ int c_pool1_len[7] = {2,2,2,1,3,3,1};
__constant__ int c_pool1_mem[7][3] = {{0,1,1},{2,3,3},{4,5,5},{6,6,6},{7,8,9},{10,11,12},{13,13,13}};
__constant__ int c_un1_len[7] = {5,5,8,4,6,6,5};
__constant__ int c_un1[7][8] = {
 {0,1,2,4,13,0,0,0},
 {0,2,3,4,13,0,0,0},
 {0,2,4,5,6,7,10,13},
 {5,6,7,10,0,0,0,0},
 {5,6,7,8,9,10,0,0},
 {5,6,7,10,11,12,0,0},
 {0,1,2,4,13,0,0,0}
};
__constant__ unsigned c_nbm1[14] = {
 0x2017u,0x2003u,0x201Du,0xCu,0x2035u,0x4F0u,0x4E0u,0x5E0u,
 0x380u,0x300u,0xCE0u,0x1C00u,0x1800u,0x2017u
};

__device__ __forceinline__ uint32 f2bf(float v) {
  uint32 u = __float_as_uint(v);
  return (u + 0x7fffu + ((u >> 16) & 1u)) >> 16;   // RNE
}
__device__ __forceinline__ uint32 swz(uint32 byteoff) {
  return byteoff ^ ((byteoff >> 3) & 16u);          // strip de-alias: bit7 -> bit4
}

// ---------------------------------------------------------------------------
// Prep: fold P (pool mean) and MASK into compact per-pool weights + biases.
// ---------------------------------------------------------------------------
__global__ void prep_fused_weights(const float* __restrict__ w0, const float* __restrict__ b0,
                                   const float* __restrict__ w1, const float* __restrict__ b1,
                                   float* __restrict__ ws) {
  int t = blockIdx.x * blockDim.x + threadIdx.x;
  if (t < N_W0C) {
    int k  = t & 15;
    int c  = (t >> 4) & 7;
    int ci = (t >> 7) & 3;
    int r  = t >> 9;
    int i  = r / 7;
    int s  = r - i * 7;
    float v = 0.f;
    if (k < 15 && s < c_un0_len[i]) {
      int m = c_un0[i][s];
      int L = c_pool0_len[i];
      for (int jj = 0; jj < L; ++jj) {
        int j = c_pool0_mem[i][jj];
        if ((c_nbm0[j] >> m) & 1u)
          v += w0[(j * 8 + c) * 1500 + (m * 4 + ci) * 15 + k];
      }
      v *= 1.f / (float)L;
    }
    ws[OFF_W0C + t] = v;
  } else if (t < N_W0C + N_W1C) {
    int t2 = t - N_W0C;
    int k  = t2 & 15;
    int c  = (t2 >> 4) & 15;
    int ci = (t2 >> 8) & 7;
    int s  = (t2 >> 11) & 7;
    int i  = t2 >> 14;
    float v = 0.f;
    if (k < 15 && s < c_un1_len[i]) {
      int m = c_un1[i][s];
      int L = c_pool1_len[i];
      for (int jj = 0; jj < L; ++jj) {
        int j = c_pool1_mem[i][jj];
        if ((c_nbm1[j] >> m) & 1u)
          v += w1[(j * 16 + c) * 1680 + (m * 8 + ci) * 15 + k];
      }
      v *= 1.f / (float)L;
    }
    ws[OFF_W1C + t2] = v;
  } else if (t < N_W0C + N_W1C + 112) {
    int p = t - (N_W0C + N_W1C);
    int i = p >> 3, c = p & 7;
    int L = c_pool0_len[i];
    float v = 0.f;
    for (int jj = 0; jj < L; ++jj) v += b0[c_pool0_mem[i][jj] * 8 + c];
    ws[OFF_BF0 + p] = v / (float)L;
  } else if (t < N_W0C + N_W1C + 224) {
    int p = t - (N_W0C + N_W1C + 112);
    int i = p >> 4, c = p & 15;
    int L = c_pool1_len[i];
    float v = 0.f;
    for (int jj = 0; jj < L; ++jj) v += b1[c_pool1_mem[i][jj] * 16 + c];
    ws[OFF_BF1 + p] = v / (float)L;
  }
}

// ---------------------------------------------------------------------------
// Stage 1: x fp32 (64,2047,100) -> y0 bf16 (64,112,1024).
// 448 threads = 112 pooled channels x 4 strips of 16 t. x staged bf16 in LDS.
// ---------------------------------------------------------------------------
__global__ __launch_bounds__(448) void conv_stage1(const float* __restrict__ x,
                                                   const float* __restrict__ ws,
                                                   ushort16* __restrict__ y0b) {
  __shared__ __align__(16) unsigned char xs[100 * S_STRIDE_B];  // 30.4 KB
  const int tid = threadIdx.x;
  const int b = blockIdx.y;
  const int t0 = blockIdx.x << 6;
  const int g0 = 2 * t0 - 7;
  const float* __restrict__ xb = x + (size_t)b * (2047 * 100);

  // staging: 100 cin x 18 chunks of 8 frames; consecutive lanes -> consecutive
  // cin (coalesced global), one swizzled ds_write_b128 each.
  for (int e = tid; e < 1800; e += 448) {
    int cin = e % 100;
    int chunk = e / 100;
    int f0 = g0 + (chunk << 3);
    uint32 u[4];
#pragma unroll
    for (int j = 0; j < 4; ++j) {
      int fa = f0 + 2 * j, fb = fa + 1;
      float va = (fa >= 0 && fa < 2047) ? xb[fa * 100 + cin] : 0.f;
      float vb = (fb >= 0 && fb < 2047) ? xb[fb * 100 + cin] : 0.f;
      u[j] = f2bf(va) | (f2bf(vb) << 16);
    }
    uint32 off = swz((uint32)(cin * S_STRIDE_B + (chunk << 4)));
    *reinterpret_cast<uint4*>(xs + off) = make_uint4(u[0], u[1], u[2], u[3]);
  }
  __syncthreads();

  const int vp = tid >> 2;
  const int tt0 = (tid & 3) << 4;
  const int i = c_order0[vp >> 3];
  const int c = vp & 7;
  float acc[16];
#pragma unroll
  for (int q = 0; q < 16; ++q) acc[q] = 0.f;

  const int len = c_un0_len[i];
  const float* __restrict__ W0c = ws + OFF_W0C;
  for (int s = 0; s < len; ++s) {
    const int m = c_un0[i][s];
#pragma unroll
    for (int ci = 0; ci < 4; ++ci) {
      const uint32 rowb = (uint32)((m * 4 + ci) * S_STRIDE_B) + ((uint32)tt0 << 2);
      uint32 ux[24];
#pragma unroll
      for (int q = 0; q < 6; ++q) {
        uint4 v = *reinterpret_cast<const uint4*>(xs + swz(rowb + (q << 4)));
        ux[4*q+0] = v.x; ux[4*q+1] = v.y; ux[4*q+2] = v.z; ux[4*q+3] = v.w;
      }
      float xf[48];
#pragma unroll
      for (int w = 0; w < 24; ++w) {
        xf[2*w]   = __uint_as_float(ux[w] << 16);
        xf[2*w+1] = __uint_as_float(ux[w] & 0xffff0000u);
      }
      const float* wp = W0c + ((((i * 7 + s) * 4 + ci) * 8 + c) << 4);
      float wk[16];
#pragma unroll
      for (int q = 0; q < 4; ++q) {
        float4 v4 = *reinterpret_cast<const float4*>(wp + 4 * q);
        wk[4*q+0] = v4.x; wk[4*q+1] = v4.y; wk[4*q+2] = v4.z; wk[4*q+3] = v4.w;
      }
#pragma unroll
      for (int k = 0; k < 15; ++k)
#pragma unroll
        for (int tt = 0; tt < 16; ++tt)
          acc[tt] = fmaf(wk[k], xf[2 * tt + k], acc[tt]);
    }
  }
  const int p = (i << 3) + c;
  const float bb = ws[OFF_BF0 + p];
  uint32 po[8];
#pragma unroll
  for (int q = 0; q < 8; ++q) {
    float o0 = fmaxf(acc[2*q]   + bb, 0.f);
    float o1 = fmaxf(acc[2*q+1] + bb, 0.f);
    po[q] = f2bf(o0) | (f2bf(o1) << 16);
  }
  ushort16* yp = y0b + (((size_t)b * 112 + p) << 10) + t0 + tt0;
  *reinterpret_cast<uint4*>(yp)     = make_uint4(po[0], po[1], po[2], po[3]);
  *reinterpret_cast<uint4*>(yp + 8) = make_uint4(po[4], po[5], po[6], po[7]);
}

// ---------------------------------------------------------------------------
// Stage 2: y0 bf16 (64,112,1024) -> out fp32 (64,112,512). One wave per pool.
// ---------------------------------------------------------------------------
__global__ __launch_bounds__(448) void conv_stage2(const float* __restrict__ ws,
                                                   const ushort16* __restrict__ y0b,
                                                   float* __restrict__ out) {
  __shared__ __align__(16) unsigned char xs[112 * S_STRIDE_B];  // 34.0 KB
  const int tid = threadIdx.x;
  const int b = blockIdx.y;
  const int t0 = blockIdx.x << 6;
  const int g0 = 2 * t0 - 7;
  const ushort16* __restrict__ yb = y0b + (size_t)b * (112 * 1024);

  for (int e = tid; e < 2016; e += 448) {
    int cin = e % 112;
    int chunk = e / 112;
    const ushort16* r = yb + (cin << 10);
    int f0 = g0 + (chunk << 3);
    uint32 u[4];
#pragma unroll
    for (int j = 0; j < 4; ++j) {
      int fa = f0 + 2 * j, fb = fa + 1;
      uint32 a = (fa >= 0 && fa < 1024) ? (uint32)r[fa] : 0u;
      uint32 d = (fb >= 0 && fb < 1024) ? (uint32)r[fb] : 0u;
      u[j] = a | (d << 16);
    }
    uint32 off = swz((uint32)(cin * S_STRIDE_B + (chunk << 4)));
    *reinterpret_cast<uint4*>(xs + off) = make_uint4(u[0], u[1], u[2], u[3]);
  }
  __syncthreads();

  const int vp = tid >> 2;
  const int tt0 = (tid & 3) << 4;
  const int i = vp >> 4;      // one pool per wave
  const int c = vp & 15;
  float acc[16];
#pragma unroll
  for (int q = 0; q < 16; ++q) acc[q] = 0.f;

  const int len = c_un1_len[i];
  const float* __restrict__ W1c = ws + OFF_W1C;
  for (int s = 0; s < len; ++s) {
    const int m = c_un1[i][s];
#pragma unroll
    for (int ci = 0; ci < 8; ++ci) {
      const uint32 rowb = (uint32)((m * 8 + ci) * S_STRIDE_B) + ((uint32)tt0 << 2);
      uint32 ux[24];
#pragma unroll
      for (int q = 0; q < 6; ++q) {
        uint4 v = *reinterpret_cast<const uint4*>(xs + swz(rowb + (q << 4)));
        ux[4*q+0] = v.x; ux[4*q+1] = v.y; ux[4*q+2] = v.z; ux[4*q+3] = v.w;
      }
      float xf[48];
#pragma unroll
      for (int w = 0; w < 24; ++w) {
        xf[2*w]   = __uint_as_float(ux[w] << 16);
        xf[2*w+1] = __uint_as_float(ux[w] & 0xffff0000u);
      }
      const float* wp = W1c + ((((i * 8 + s) * 8 + ci) * 16 + c) << 4);
      float wk[16];
#pragma unroll
      for (int q = 0; q < 4; ++q) {
        float4 v4 = *reinterpret_cast<const float4*>(wp + 4 * q);
        wk[4*q+0] = v4.x; wk[4*q+1] = v4.y; wk[4*q+2] = v4.z; wk[4*q+3] = v4.w;
      }
#pragma unroll
      for (int k = 0; k < 15; ++k)
#pragma unroll
        for (int tt = 0; tt < 16; ++tt)
          acc[tt] = fmaf(wk[k], xf[2 * tt + k], acc[tt]);
    }
  }
  const int p = (i << 4) + c;
  const float bb = ws[OFF_BF1 + p];
  float* __restrict__ op = out + (((size_t)b * 112 + p) << 9) + t0 + tt0;
#pragma unroll
  for (int q = 0; q < 4; ++q) {
    float4 o;
    o.x = fmaxf(acc[4*q+0] + bb, 0.f);
    o.y = fmaxf(acc[4*q+1] + bb, 0.f);
    o.z = fmaxf(acc[4*q+2] + bb, 0.f);
    o.w = fmaxf(acc[4*q+3] + bb, 0.f);
    *reinterpret_cast<float4*>(op + 4 * q) = o;
  }
}

extern "C" void kernel_launch(void* const* d_in, const int* in_sizes, int n_in,
                              void* d_out, int out_size, void* d_ws, size_t ws_size,
                              hipStream_t stream) {
  const float* x  = (const float*)d_in[0];
  const float* w0 = (const float*)d_in[1];
  const float* b0 = (const float*)d_in[2];
  const float* w1 = (const float*)d_in[3];
  const float* b1 = (const float*)d_in[4];
  float* ws  = (float*)d_ws;
  ushort16* y0b = (ushort16*)((char*)d_ws + OFF_Y0B);
  float* out = (float*)d_out;

  const int prep_total = N_W0C + N_W1C + 224;
  prep_fused_weights<<<(prep_total + 255) / 256, 256, 0, stream>>>(w0, b0, w1, b1, ws);
  conv_stage1<<<dim3(16, 64), 448, 0, stream>>>(x, ws, y0b);
  conv_stage2<<<dim3(8, 64), 448, 0, stream>>>(ws, y0b, out);
}

// Round 3
// 61.282 us; speedup vs baseline: 4.0497x; 3.3943x over previous
//
#include <hip/hip_runtime.h>

// ---------------------------------------------------------------------------
// DynamicEncoder via MFMA (gfx950, mfma_f32_16x16x32_bf16).
//
// Stage1: x (64, T=2047(+1 zero frame), 100ch) -> y0 bf16 [b][1024 t][112 ch]
//   7 pool-PAIRS, each pair's union <= 8 nodes x 4 ci = 32 cin = one K-step.
//   Wave g computes out-chs of pair g (M=16) for 64 t (4 n-tiles), 15 taps.
// Stage2: y0 -> out fp32 (64, 112, 512)
//   7 pools (M=16 each), union <= 8 nodes x 8 ci = 64 cin = 2 K-steps.
//
// Weights pre-folded (mask * pool-mean) into A-fragment lane layout:
//   A-frag lane l elem j = W[m = l&15][slot = (l>>4)*8 + j], bf16.
// B-frag lane l elem j = X[slot][t = l&15] read from linear [frame][cin] LDS.
//
// Workspace (bytes):
//   A1  @ 0      : [7 g][15 k][64 lane][8] bf16 = 107520
//   A2  @ 107520 : [7 p][2 ks][15 k][64][8] bf16 = 215040
//   BF0 @ 322560 : 112 f32 ; BF1 @ 323008 : 112 f32
//   Y0  @ 323584 : [64 b][1024 t][112 ch] bf16 = 14680064
// ---------------------------------------------------------------------------

#define OFF_A2  107520u
#define OFF_BF0 322560u
#define OFF_BF1 323008u
#define OFF_Y0  323584u

typedef unsigned int uint32;
typedef __attribute__((ext_vector_type(8))) short bs8;
typedef __attribute__((ext_vector_type(4))) float f32x4;
union U8 { uint4 u; bs8 s; };

// ---- graph constants (verified rounds 1-2) ----
__constant__ int c_pool0_len[14] = {2,2,2,2,1,2,2,1,2,2,1,2,2,2};
__constant__ int c_pool0_mem[14][2] = {{0,3},{6,9},{1,4},{7,10},{2,2},{5,8},{11,14},{12,12},
                                       {15,17},{19,21},{13,13},{16,18},{20,22},{23,24}};
__constant__ unsigned c_nbm0[25] = {
 0x180000Fu,0x1800017u,0x1800027u,0x1800049u,0x92u,0x124u,0x248u,0x490u,
 0x3920u,0x240u,0x480u,0x7900u,0xB900u,0x13900u,0x4800u,0x29000u,
 0x52000u,0xA8000u,0x150000u,0x2A0000u,0x540000u,0x280000u,0x500000u,
 0x180000Fu,0x180000Fu
};
__constant__ int c_pool1_len[7] = {2,2,2,1,3,3,1};
__constant__ int c_pool1_mem[7][3] = {{0,1,1},{2,3,3},{4,5,5},{6,6,6},{7,8,9},{10,11,12},{13,13,13}};
__constant__ unsigned c_nbm1[14] = {
 0x2017u,0x2003u,0x201Du,0xCu,0x2035u,0x4F0u,0x4E0u,0x5E0u,
 0x380u,0x300u,0xCE0u,0x1C00u,0x1800u,0x2017u
};
// stage1 pool pairs and their combined unions (pad node 25 = zero channels)
__constant__ int c_g1p[7][2] = {{0,13},{1,3},{2,4},{5,6},{7,10},{8,11},{9,12}};
__constant__ int c_U1[7][8] = {
 {0,1,2,3,6,23,24,25},
 {3,4,6,7,9,10,25,25},
 {0,1,2,4,5,7,23,24},
 {2,5,8,11,12,13,14,25},
 {8,11,12,13,15,16,25,25},
 {12,13,15,16,17,18,19,20},
 {17,18,19,20,21,22,25,25}};
// stage2 unions (pad node 14 = zero channels)
__constant__ int c_U2[7][8] = {
 {0,1,2,4,13,14,14,14},
 {0,2,3,4,13,14,14,14},
 {0,2,4,5,6,7,10,13},
 {5,6,7,10,14,14,14,14},
 {5,6,7,8,9,10,14,14},
 {5,6,7,10,11,12,14,14},
 {0,1,2,4,13,14,14,14}};
// packed per-lane-group LDS byte offsets (node*8 stage1, node*16 stage2)
__constant__ unsigned c_pk1a[7] = {0xC0301000u,0xC8483018u,0xB8281000u,0x70604010u,
                                   0xC8786040u,0x98887860u,0xC8A89888u};
__constant__ unsigned c_pk1b[7] = {0xC8B81808u,0xC8503820u,0xC0382008u,0xC8685828u,
                                   0xC8806858u,0xA0908068u,0xC8B0A090u};
__constant__ unsigned c_pk2[7][2] = {
 {0x40201000u,0xE0E0E0D0u},{0x40302000u,0xE0E0E0D0u},{0x50402000u,0xD0A07060u},
 {0xA0706050u,0xE0E0E0E0u},{0x80706050u,0xE0E0A090u},{0xA0706050u,0xE0E0C0B0u},
 {0x40201000u,0xE0E0E0D0u}};

__device__ __forceinline__ uint32 f2bf(float v) {
  uint32 u = __float_as_uint(v);
  return (u + 0x7fffu + ((u >> 16) & 1u)) >> 16;   // RNE
}

// ---------------------------------------------------------------------------
// Prep: bake fused (mask x pool-mean) weights straight into A-fragment order.
// ---------------------------------------------------------------------------
__global__ void prep_fused_weights(const float* __restrict__ w0, const float* __restrict__ b0,
                                   const float* __restrict__ w1, const float* __restrict__ b1,
                                   char* __restrict__ wsb) {
  int t = blockIdx.x * blockDim.x + threadIdx.x;
  if (t < 6720) {                       // A1: [7 g][15 k][64 lane] uint4
    int lane = t & 63;
    int r = t >> 6;
    int k = r % 15, g = r / 15;
    int m = lane & 15, h = lane >> 4;
    int pool = (m < 8) ? c_g1p[g][0] : c_g1p[g][1];
    int c = m & 7;
    int L = c_pool0_len[pool];
    float inv = 1.f / (float)L;
    uint32 us[8];
#pragma unroll
    for (int j = 0; j < 8; ++j) {
      int node = c_U1[g][2 * h + (j >> 2)];
      int ci = j & 3;
      float v = 0.f;
      if (node < 25) {
        for (int jj = 0; jj < L; ++jj) {
          int mem = c_pool0_mem[pool][jj];
          if ((c_nbm0[mem] >> node) & 1u)
            v += w0[(mem * 8 + c) * 1500 + (node * 4 + ci) * 15 + k];
        }
        v *= inv;
      }
      us[j] = f2bf(v);
    }
    uint4 o = make_uint4(us[0] | (us[1] << 16), us[2] | (us[3] << 16),
                         us[4] | (us[5] << 16), us[6] | (us[7] << 16));
    reinterpret_cast<uint4*>(wsb)[t] = o;
  } else if (t < 6720 + 13440) {        // A2: [7 p][2 ks][15 k][64 lane] uint4
    int t2 = t - 6720;
    int lane = t2 & 63;
    int r = t2 >> 6;
    int k = r % 15;
    int r2 = r / 15;
    int ks = r2 & 1, p = r2 >> 1;
    int c = lane & 15, h = lane >> 4;
    int node = c_U2[p][ks * 4 + h];
    int L = c_pool1_len[p];
    float inv = 1.f / (float)L;
    uint32 us[8];
#pragma unroll
    for (int j = 0; j < 8; ++j) {
      float v = 0.f;
      if (node < 14) {
        for (int jj = 0; jj < L; ++jj) {
          int mem = c_pool1_mem[p][jj];
          if ((c_nbm1[mem] >> node) & 1u)
            v += w1[(mem * 16 + c) * 1680 + (node * 8 + j) * 15 + k];
        }
        v *= inv;
      }
      us[j] = f2bf(v);
    }
    uint4 o = make_uint4(us[0] | (us[1] << 16), us[2] | (us[3] << 16),
                         us[4] | (us[5] << 16), us[6] | (us[7] << 16));
    reinterpret_cast<uint4*>(wsb + OFF_A2)[t2] = o;
  } else if (t < 6720 + 13440 + 112) {  // BF0
    int p = t - (6720 + 13440);
    int i = p >> 3, c = p & 7;
    int L = c_pool0_len[i];
    float v = 0.f;
    for (int jj = 0; jj < L; ++jj) v += b0[c_pool0_mem[i][jj] * 8 + c];
    reinterpret_cast<float*>(wsb + OFF_BF0)[p] = v / (float)L;
  } else if (t < 6720 + 13440 + 224) {  // BF1
    int p = t - (6720 + 13440 + 112);
    int i = p >> 4, c = p & 15;
    int L = c_pool1_len[i];
    float v = 0.f;
    for (int jj = 0; jj < L; ++jj) v += b1[c_pool1_mem[i][jj] * 16 + c];
    reinterpret_cast<float*>(wsb + OFF_BF1)[p] = v / (float)L;
  }
}

// ---------------------------------------------------------------------------
// Stage 1: 448 thr = 7 waves (wave = pool pair). t-tile 64, LDS [141 f][116 ch]
// bf16, row stride 232 B. Output transposed in LDS -> y0 [b][t][112] bf16.
// ---------------------------------------------------------------------------
__global__ __launch_bounds__(448, 7) void conv_stage1(const float* __restrict__ x,
                                                      const char* __restrict__ wsb,
                                                      char* __restrict__ y0b) {
  __shared__ __align__(16) unsigned char xs[141 * 232];  // 32.7 KB
  const int tid = threadIdx.x;
  const int b = blockIdx.y;
  const int t0 = blockIdx.x << 6;
  const int g0 = 2 * t0 - 7;
  const float* __restrict__ xb = x + (size_t)b * (2047 * 100);

  // stage: frame-major copy, fp32 -> bf16. q<25: data (cin 4q..4q+3); q 25..28: zero pad.
  for (int e = tid; e < 141 * 32; e += 448) {
    int f = e >> 5, q = e & 31;
    if (q >= 29) continue;
    uint2 w = make_uint2(0u, 0u);
    int gt = g0 + f;
    if (q < 25 && (unsigned)gt < 2047u) {
      float4 v = *reinterpret_cast<const float4*>(xb + gt * 100 + 4 * q);
      w.x = f2bf(v.x) | (f2bf(v.y) << 16);
      w.y = f2bf(v.z) | (f2bf(v.w) << 16);
    }
    *reinterpret_cast<uint2*>(xs + f * 232 + q * 8) = w;
  }
  __syncthreads();

  const int lane = tid & 63;
  const int g = tid >> 6;            // wave = pair index 0..6
  const int m16 = lane & 15, h = lane >> 4;
  const uint32 offA = (c_pk1a[g] >> (8 * h)) & 255u;
  const uint32 offB = (c_pk1b[g] >> (8 * h)) & 255u;
  const uint4* __restrict__ A1p = reinterpret_cast<const uint4*>(wsb);

  f32x4 acc[4];
#pragma unroll
  for (int nt = 0; nt < 4; ++nt) acc[nt] = (f32x4)0.f;

#pragma unroll 1
  for (int k = 0; k < 15; ++k) {
    U8 a; a.u = A1p[(g * 15 + k) * 64 + lane];
    const uint32 base = (uint32)((2 * m16 + k) * 232);
#pragma unroll
    for (int nt = 0; nt < 4; ++nt) {
      const uint32 ad = base + nt * (32 * 232);
      uint2 lo = *reinterpret_cast<const uint2*>(xs + ad + offA);
      uint2 hi = *reinterpret_cast<const uint2*>(xs + ad + offB);
      U8 bfr; bfr.u = make_uint4(lo.x, lo.y, hi.x, hi.y);
      acc[nt] = __builtin_amdgcn_mfma_f32_16x16x32_bf16(a.s, bfr.s, acc[nt], 0, 0, 0);
    }
  }

  // epilogue: bias+relu, pack to bf16, transpose via LDS, coalesced store.
  const int pa = c_g1p[g][0], pb = c_g1p[g][1];
  const int chbase = (h < 2) ? (pa * 8 + 4 * h) : (pb * 8 + 4 * (h - 2));
  const float4 bv = *reinterpret_cast<const float4*>(wsb + OFF_BF0 + chbase * 4);
  __syncthreads();   // all LDS reads done before overwrite
#pragma unroll
  for (int nt = 0; nt < 4; ++nt) {
    float o0 = fmaxf(acc[nt][0] + bv.x, 0.f);
    float o1 = fmaxf(acc[nt][1] + bv.y, 0.f);
    float o2 = fmaxf(acc[nt][2] + bv.z, 0.f);
    float o3 = fmaxf(acc[nt][3] + bv.w, 0.f);
    uint2 wpk = make_uint2(f2bf(o0) | (f2bf(o1) << 16), f2bf(o2) | (f2bf(o3) << 16));
    *reinterpret_cast<uint2*>(xs + (nt * 16 + m16) * 232 + chbase * 2) = wpk;
  }
  __syncthreads();
  for (int e = tid; e < 1024; e += 448) {
    int row = e >> 4, q = e & 15;
    if (q >= 14) continue;
    uint2 a = *reinterpret_cast<const uint2*>(xs + row * 232 + q * 16);
    uint2 d = *reinterpret_cast<const uint2*>(xs + row * 232 + q * 16 + 8);
    *reinterpret_cast<uint4*>(y0b + (size_t)(b * 1024 + t0 + row) * 224 + q * 16) =
        make_uint4(a.x, a.y, d.x, d.y);
  }
}

// ---------------------------------------------------------------------------
// Stage 2: 448 thr = 7 waves (wave = pool). t-tile 32, LDS [80 rows][128 ch]
// bf16 (parity-split rows, XOR swizzle), K = 2 steps of 32.
// ---------------------------------------------------------------------------
__global__ __launch_bounds__(448, 7) void conv_stage2(const char* __restrict__ wsb,
                                                      const char* __restrict__ y0b,
                                                      float* __restrict__ out) {
  __shared__ __align__(16) unsigned char xs[80 * 256];  // 20.5 KB
  const int tid = threadIdx.x;
  const int b = blockIdx.y;
  const int t0 = blockIdx.x << 5;
  const int g0 = 2 * t0 - 7;
  const char* __restrict__ yb = y0b + (size_t)b * (1024 * 224);

  // stage: row copy y0[t][112] -> LDS [pr][128] (q=14,15 zero pad nodes)
  for (int e = tid; e < 77 * 16; e += 448) {
    int f = e >> 4, q = e & 15;
    uint4 v = make_uint4(0u, 0u, 0u, 0u);
    int gt = g0 + f;
    if (q < 14 && (unsigned)gt < 1024u)
      v = *reinterpret_cast<const uint4*>(yb + (size_t)gt * 224 + q * 16);
    int pr = (f >> 1) + (f & 1) * 40;
    *reinterpret_cast<uint4*>(xs + pr * 256 + ((q * 16) ^ ((pr & 7) << 4))) = v;
  }
  __syncthreads();

  const int lane = tid & 63;
  const int p = tid >> 6;           // wave = pool 0..6
  const int m16 = lane & 15, h = lane >> 4;
  const uint4* __restrict__ A2p = reinterpret_cast<const uint4*>(wsb + OFF_A2);

  f32x4 acc[2];
  acc[0] = (f32x4)0.f; acc[1] = (f32x4)0.f;

#pragma unroll 1
  for (int ks = 0; ks < 2; ++ks) {
    const uint32 noff = (c_pk2[p][ks] >> (8 * h)) & 255u;
#pragma unroll 1
    for (int k = 0; k < 15; ++k) {
      U8 a; a.u = A2p[((p * 2 + ks) * 15 + k) * 64 + lane];
      const int prk = (k >> 1) + (k & 1) * 40;
#pragma unroll
      for (int nt = 0; nt < 2; ++nt) {
        int pr = nt * 16 + m16 + prk;
        U8 bfr;
        bfr.u = *reinterpret_cast<const uint4*>(xs + pr * 256 + (noff ^ ((pr & 7) << 4)));
        acc[nt] = __builtin_amdgcn_mfma_f32_16x16x32_bf16(a.s, bfr.s, acc[nt], 0, 0, 0);
      }
    }
  }

  const float4 bv = *reinterpret_cast<const float4*>(wsb + OFF_BF1 + (p * 16 + 4 * h) * 4);
#pragma unroll
  for (int nt = 0; nt < 2; ++nt) {
    size_t obase = ((size_t)b * 112 + p * 16 + 4 * h) * 512 + t0 + nt * 16 + m16;
    out[obase]        = fmaxf(acc[nt][0] + bv.x, 0.f);
    out[obase + 512]  = fmaxf(acc[nt][1] + bv.y, 0.f);
    out[obase + 1024] = fmaxf(acc[nt][2] + bv.z, 0.f);
    out[obase + 1536] = fmaxf(acc[nt][3] + bv.w, 0.f);
  }
}

extern "C" void kernel_launch(void* const* d_in, const int* in_sizes, int n_in,
                              void* d_out, int out_size, void* d_ws, size_t ws_size,
                              hipStream_t stream) {
  const float* x  = (const float*)d_in[0];
  const float* w0 = (const float*)d_in[1];
  const float* b0 = (const float*)d_in[2];
  const float* w1 = (const float*)d_in[3];
  const float* b1 = (const float*)d_in[4];
  char* wsb = (char*)d_ws;
  float* out = (float*)d_out;

  prep_fused_weights<<<80, 256, 0, stream>>>(w0, b0, w1, b1, wsb);
  conv_stage1<<<dim3(16, 64), 448, 0, stream>>>(x, wsb, wsb + OFF_Y0);
  conv_stage2<<<dim3(16, 64), 448, 0, stream>>>(wsb, wsb + OFF_Y0, out);
}